// Round 8
// baseline (184.788 us; speedup 1.0000x reference)
//
#include <hip/hip_runtime.h>
#include <math.h>

#define N 4096
#define D 512
#define NUM_STEPS 151
#define HALF_BINS 75
#define INV_STEP 75.0f
#define NUM_CLASSES 751
#define P_TOTAL 8386560.0f   // N*(N-1)/2, exact in fp32 (< 2^24)
#define TILES_1D 32          // 4096 / 128
#define NTILES (TILES_1D * (TILES_1D + 1) / 2)   // 528

// ws layout (float/int indices into d_ws)
#define WS_SUM_ALL 0
#define WS_POS_CNT 1          // int (total pos pairs, written by prep's sort block)
#define WS_SUM_POS 2
#define WS_S_POS   3
#define WS_DONE    4          // int (gram done-counter, zeroed by memset)
#define WS_G_OFF   8          // 151 floats
#define WS_LIST_OFF 1024      // posS, MAXP floats
#define MAXP (1 << 18)
#define WS_PAIR_OFF (WS_LIST_OFF + MAXP)          // MAXP int2 pair row-indices
#define WS_FEAT_OFF (WS_PAIR_OFF + 2 * MAXP)      // 4096x512 fp32 normalized feats
#define WS_FEATB_OFF (WS_FEAT_OFF + N * D)        // 4096x512 bf16 normalized feats

typedef __bf16 bf16x8 __attribute__((ext_vector_type(8)));
typedef float floatx4 __attribute__((ext_vector_type(4)));

// global->LDS async DMA, 16B per lane; LDS dest = wave-uniform base + lane*16
__device__ __forceinline__ void load_lds16(const void* g, void* s) {
    __builtin_amdgcn_global_load_lds(
        (const __attribute__((address_space(1))) void*)g,
        (__attribute__((address_space(3))) void*)s, 16, 0, 0);
}

// ---------------- K1: fused normalize (blocks 0..N-1) + sort/pair-list (block N) ----------------
__global__ __launch_bounds__(256) void k_prep(const float* __restrict__ feat,
                                              const int* __restrict__ cls,
                                              float* __restrict__ nf,
                                              __bf16* __restrict__ nfb,
                                              int2* __restrict__ pairRows,
                                              int* __restrict__ posCntOut,
                                              float* __restrict__ sPosOut) {
    __shared__ int shmem[NUM_CLASSES * 3 + N / 4];  // sort block scratch (~18.2 KB)
    __shared__ int wsumR[4], wsumP[4];
    __shared__ float wsumF[4];
    int t = threadIdx.x;

    if (blockIdx.x < N) {
        // ---- normalize ----
        int row = blockIdx.x;
        const float* fr = feat + (size_t)row * D;
        float a = fr[t];
        float b = fr[t + 256];
        float ss = a * a + b * b;
        for (int o = 32; o > 0; o >>= 1) ss += __shfl_down(ss, o, 64);
        int lane = t & 63, wid = t >> 6;
        if (lane == 0) wsumF[wid] = ss;
        __syncthreads();
        float tot = wsumF[0] + wsumF[1] + wsumF[2] + wsumF[3];
        float inv = 1.0f / sqrtf(tot);
        float na = a * inv, nb = b * inv;
        nf[(size_t)row * D + t] = na;
        nf[(size_t)row * D + t + 256] = nb;
        nfb[(size_t)row * D + t] = (__bf16)na;
        nfb[(size_t)row * D + t + 256] = (__bf16)nb;
        return;
    }

    // ---- sort block: counting sort + prefix sums + flat pair list ----
    int* hcnt = shmem;
    int* hoff = shmem + NUM_CLASSES;
    int* poff = shmem + 2 * NUM_CLASSES;
    // rowIdx in LDS: reuse tail (N=4096 ints); shmem sized 3*751 + 1024 ints = 3277 ints
    // -> not enough for 4096; use a dedicated static array instead:
    __shared__ int rowIdxL[N / 2];   // 2048 ints... (see packing below)
    // NOTE: classes ~751, rows 4096 -> we store rowIdx in LDS as 4096 shorts packed in 2048 ints
    // row index < 4096 fits in 16 bits.
    for (int c = t; c < NUM_CLASSES; c += 256) hcnt[c] = 0;
    __syncthreads();
    for (int n = t; n < N; n += 256) atomicAdd(&hcnt[cls[n]], 1);
    __syncthreads();

    int c0 = t * 3;
    int cntPreR[3], cntPreP[3];
    int myR = 0, myP = 0;
    #pragma unroll
    for (int k = 0; k < 3; ++k) {
        int c = c0 + k;
        int cnt = (c < NUM_CLASSES) ? hcnt[c] : 0;
        cntPreR[k] = myR; cntPreP[k] = myP;
        myR += cnt;
        myP += cnt * (cnt - 1) / 2;
    }
    int lane = t & 63, wv = t >> 6;
    int incR = myR, incP = myP;
    for (int o = 1; o < 64; o <<= 1) {
        int rr = __shfl_up(incR, o, 64);
        int pp = __shfl_up(incP, o, 64);
        if (lane >= o) { incR += rr; incP += pp; }
    }
    if (lane == 63) { wsumR[wv] = incR; wsumP[wv] = incP; }
    __syncthreads();
    int baseR = 0, baseP = 0;
    for (int w = 0; w < wv; ++w) { baseR += wsumR[w]; baseP += wsumP[w]; }
    int exR = baseR + incR - myR;
    int exP = baseP + incP - myP;
    #pragma unroll
    for (int k = 0; k < 3; ++k) {
        int c = c0 + k;
        if (c < NUM_CLASSES) { hoff[c] = exR + cntPreR[k]; poff[c] = exP + cntPreP[k]; }
    }
    __syncthreads();

    // scatter rows grouped by class into packed 16-bit slots
    for (int c = t; c < NUM_CLASSES; c += 256) hcnt[c] = hoff[c];   // cursors
    __syncthreads();
    for (int n = t; n < N; n += 256) {
        int p = atomicAdd(&hcnt[cls[n]], 1);
        // pack 16-bit row id at slot p
        int word = p >> 1, sh = (p & 1) * 16;
        atomicAnd(&rowIdxL[word], ~(0xFFFF << sh));
        atomicOr(&rowIdxL[word], (n & 0xFFFF) << sh);
    }
    __syncthreads();

    // build flat pair list
    for (int c = t; c < NUM_CLASSES; c += 256) {
        int o0 = hoff[c];
        int nc = (c + 1 < NUM_CLASSES ? hoff[c + 1]
                                      : wsumR[0] + wsumR[1] + wsumR[2] + wsumR[3]) - o0;
        int pb = poff[c];
        int idx = 0;
        for (int a = 0; a < nc - 1; ++a) {
            int sa = o0 + a;
            int ra = (rowIdxL[sa >> 1] >> ((sa & 1) * 16)) & 0xFFFF;
            for (int b = a + 1; b < nc; ++b) {
                int sb = o0 + b;
                int rb = (rowIdxL[sb >> 1] >> ((sb & 1) * 16)) & 0xFFFF;
                pairRows[pb + idx] = make_int2(ra, rb);
                ++idx;
            }
        }
    }
    if (t == 0) {
        int totP = wsumP[0] + wsumP[1] + wsumP[2] + wsumP[3];
        *posCntOut = totP;
        *sPosOut = (float)totP;
    }
}

// ---------------- K2: pair sims over flat list, 1 pair per wave-iteration ----------------
__global__ __launch_bounds__(256) void k_pospairs4(const float* __restrict__ nf,
                                                   const int2* __restrict__ pairRows,
                                                   const int* __restrict__ posCnt,
                                                   float* __restrict__ posS) {
    int nP = *posCnt;
    if (nP > MAXP) nP = MAXP;
    int gw = (blockIdx.x * 256 + threadIdx.x) >> 6;   // global wave id, 0..4095
    int lane = threadIdx.x & 63;
    for (int p = gw; p < nP; p += 4096) {
        int2 pr = pairRows[p];
        const float4* x4 = (const float4*)(nf + (size_t)pr.x * D);
        const float4* y4 = (const float4*)(nf + (size_t)pr.y * D);
        float4 xa = x4[lane * 2], xb = x4[lane * 2 + 1];
        float4 ya = y4[lane * 2], yb = y4[lane * 2 + 1];
        float s = xa.x * ya.x + xa.y * ya.y + xa.z * ya.z + xa.w * ya.w
                + xb.x * yb.x + xb.y * yb.y + xb.z * yb.z + xb.w * yb.w;
        for (int o = 32; o > 0; o >>= 1) s += __shfl_down(s, o, 64);
        if (lane == 0) posS[p] = s;
    }
}

// ---------------- K3: hist_pos -> cdf -> G table, plus sum_pos g ----------------
__global__ __launch_bounds__(256) void k_build_cdf(const float* __restrict__ posS,
                                                   const int* __restrict__ posCnt,
                                                   float* __restrict__ G,
                                                   float* __restrict__ sumPosOut) {
    __shared__ float hist[NUM_STEPS];
    __shared__ float Gs[NUM_STEPS];
    int t = threadIdx.x;
    int C = *posCnt;
    if (C > MAXP) C = MAXP;
    for (int b = t; b < NUM_STEPS; b += 256) hist[b] = 0.f;
    __syncthreads();
    for (int p = t; p < C; p += 256) {
        float s = posS[p];
        float x = s * INV_STEP;
        float kf = floorf(x);
        float frac = x - kf;
        int kI = (int)kf;
        int lo = min(max(kI + HALF_BINS, 0), NUM_STEPS - 1);
        int hi = min(max(kI + HALF_BINS + 1, 0), NUM_STEPS - 1);
        atomicAdd(&hist[lo], 1.0f - frac);
        atomicAdd(&hist[hi], frac);
    }
    __syncthreads();
    if (t == 0) {
        float invC = (C > 0) ? (1.0f / (float)C) : 0.f;
        float acc = 0.f;
        for (int b = 0; b < NUM_STEPS; ++b) {
            acc += hist[b];
            Gs[b] = acc * invC;
        }
    }
    __syncthreads();
    for (int b = t; b < NUM_STEPS; b += 256) G[b] = Gs[b];
    float ps = 0.f;
    for (int p = t; p < C; p += 256) {
        float s = posS[p];
        float x = s * INV_STEP;
        float kf = floorf(x);
        float frac = x - kf;
        int kI = (int)kf;
        int lo = min(max(kI + HALF_BINS, 0), NUM_STEPS - 1);
        int hi = min(max(kI + HALF_BINS + 1, 0), NUM_STEPS - 1);
        ps += (1.f - frac) * Gs[lo] + frac * Gs[hi];
    }
    for (int o = 32; o > 0; o >>= 1) ps += __shfl_down(ps, o, 64);
    __shared__ float wsum[4];
    int lane = t & 63, wid = t >> 6;
    if (lane == 0) wsum[wid] = ps;
    __syncthreads();
    if (t == 0) *sumPosOut = wsum[0] + wsum[1] + wsum[2] + wsum[3];
}

// ---------------- K4: 128x128 MFMA Gram, BK=64 (8 K-steps), fused final ----------------
// LDS: 16 panels/matrix; panel pid=(rp<<1)|kc holds rows rp*16..+15, k-chunk kc*32..+31
// in MFMA fragment lane order: element (row = L&15, k = (L>>4)*8 + j) at pid*512 + L*8 + j.
__global__ __launch_bounds__(256) void k_gram(const __bf16* __restrict__ nfb,
                                              const float* __restrict__ G,
                                              float* __restrict__ sumAll,
                                              const float* __restrict__ wsf,
                                              int* __restrict__ done,
                                              float* __restrict__ out) {
    int bid = blockIdx.x;
    int ti = 0, rem = bid;
    while (rem >= TILES_1D - ti) { rem -= TILES_1D - ti; ++ti; }
    int tj = ti + rem;

    __shared__ __align__(16) __bf16 As[16 * 512];   // 16 KiB
    __shared__ __align__(16) __bf16 Bs[16 * 512];
    __shared__ float Gs[NUM_STEPS];

    int tid = threadIdx.x;
    for (int b = tid; b < NUM_STEPS; b += 256) Gs[b] = G[b];

    int lane = tid & 63;
    int wave = tid >> 6;
    int rowA0 = ti * 128, rowB0 = tj * 128;

    // staging: wave stages panels wave*4..wave*4+3 of A and of B
    int fr2 = lane & 15, kc2 = lane >> 4;   // kc2*8 = k offset within 32-chunk
    const __bf16* gA[4];
    const __bf16* gB[4];
    __bf16* lA[4];
    __bf16* lB[4];
    #pragma unroll
    for (int i = 0; i < 4; ++i) {
        int pid = wave * 4 + i;
        int rp = pid >> 1, kc = pid & 1;
        gA[i] = nfb + (size_t)(rowA0 + rp * 16 + fr2) * D + kc * 32 + kc2 * 8;
        gB[i] = nfb + (size_t)(rowB0 + rp * 16 + fr2) * D + kc * 32 + kc2 * 8;
        lA[i] = &As[pid * 512];
        lB[i] = &Bs[pid * 512];
    }

    int pbA = (wave >> 1) * 4;   // wave's A row-panels
    int pbB = (wave & 1) * 4;    // wave's B row-panels

    floatx4 acc[4][4] = {};

    for (int kb = 0; kb < D / 64; ++kb) {
        int kbase = kb * 64;
        #pragma unroll
        for (int i = 0; i < 4; ++i) {
            load_lds16(gA[i] + kbase, lA[i]);
            load_lds16(gB[i] + kbase, lB[i]);
        }
        __syncthreads();

        #pragma unroll
        for (int kc = 0; kc < 2; ++kc) {
            bf16x8 a[4], b[4];
            #pragma unroll
            for (int r = 0; r < 4; ++r)
                a[r] = *(const bf16x8*)(&As[((pbA + r) * 2 + kc) * 512 + lane * 8]);
            #pragma unroll
            for (int c = 0; c < 4; ++c)
                b[c] = *(const bf16x8*)(&Bs[((pbB + c) * 2 + kc) * 512 + lane * 8]);
            #pragma unroll
            for (int r = 0; r < 4; ++r)
                #pragma unroll
                for (int c = 0; c < 4; ++c)
                    acc[r][c] = __builtin_amdgcn_mfma_f32_16x16x32_bf16(a[r], b[c], acc[r][c], 0, 0, 0);
        }
        __syncthreads();
    }

    // epilogue: g(s) lookup with upper-triangle mask
    // C/D layout (16x16x32): col = lane&15 (B index), row = (lane>>4)*4 + reg (A index)
    int crow = (lane >> 4) * 4;
    int ccol = lane & 15;
    int wm = pbA * 16, wn = pbB * 16;
    float gsum = 0.f;
    #pragma unroll
    for (int r = 0; r < 4; ++r) {
        #pragma unroll
        for (int c = 0; c < 4; ++c) {
            #pragma unroll
            for (int reg = 0; reg < 4; ++reg) {
                int gi = rowA0 + wm + r * 16 + crow + reg;
                int gj = rowB0 + wn + c * 16 + ccol;
                if (gi < gj) {
                    float s = acc[r][c][reg];
                    float x = s * INV_STEP;
                    float kf = floorf(x);
                    float frac = x - kf;
                    int kI = (int)kf;
                    int lo = min(max(kI + HALF_BINS, 0), NUM_STEPS - 1);
                    int hi = min(max(kI + HALF_BINS + 1, 0), NUM_STEPS - 1);
                    gsum += (1.f - frac) * Gs[lo] + frac * Gs[hi];
                }
            }
        }
    }
    for (int o = 32; o > 0; o >>= 1) gsum += __shfl_down(gsum, o, 64);
    __shared__ float wsum[4];
    if ((tid & 63) == 0) wsum[tid >> 6] = gsum;
    __syncthreads();
    if (tid == 0) {
        atomicAdd(sumAll, wsum[0] + wsum[1] + wsum[2] + wsum[3]);
        __threadfence();
        int d = atomicAdd(done, 1);
        if (d == NTILES - 1) {
            // last block: all sumAll atomics are globally visible (device-scope)
            float sAll = atomicAdd(sumAll, 0.0f);   // coherent read
            float sPos = wsf[WS_SUM_POS];
            float C = wsf[WS_S_POS];
            out[0] = (sAll - sPos) / (P_TOTAL - C);
        }
    }
}

extern "C" void kernel_launch(void* const* d_in, const int* in_sizes, int n_in,
                              void* d_out, int out_size, void* d_ws, size_t ws_size,
                              hipStream_t stream) {
    const float* feat = (const float*)d_in[0];
    const int* cls = (const int*)d_in[1];
    float* out = (float*)d_out;
    float* wsf = (float*)d_ws;
    int* wsi = (int*)d_ws;

    hipMemsetAsync(d_ws, 0, 4096, stream);   // zeroes sumAll/done/counters/G header

    float* nf = wsf + WS_FEAT_OFF;
    __bf16* nfb = (__bf16*)(wsf + WS_FEATB_OFF);
    float* posS = wsf + WS_LIST_OFF;
    int2* pairRows = (int2*)(wsi + WS_PAIR_OFF);
    float* G = wsf + WS_G_OFF;

    k_prep<<<N + 1, 256, 0, stream>>>(feat, cls, nf, nfb, pairRows,
                                      wsi + WS_POS_CNT, wsf + WS_S_POS);
    k_pospairs4<<<1024, 256, 0, stream>>>(nf, pairRows, wsi + WS_POS_CNT, posS);
    k_build_cdf<<<1, 256, 0, stream>>>(posS, wsi + WS_POS_CNT, G, wsf + WS_SUM_POS);
    k_gram<<<NTILES, 256, 0, stream>>>(nfb, G, wsf + WS_SUM_ALL, wsf,
                                       wsi + WS_DONE, out);
}

// Round 9
// 172.771 us; speedup vs baseline: 1.0696x; 1.0696x over previous
//
#include <hip/hip_runtime.h>
#include <math.h>

#define N 4096
#define D 512
#define NUM_STEPS 151
#define HALF_BINS 75
#define INV_STEP 75.0f
#define NUM_CLASSES 751
#define P_TOTAL 8386560.0f   // N*(N-1)/2, exact in fp32 (< 2^24)
#define GTILES 64            // 4096 / 64 tiles per dim
#define NTILES (GTILES * (GTILES + 1) / 2)   // 2080 upper-tri 64x64 tiles

// ws layout (float/int indices into d_ws)
#define WS_SUM_ALL 0
#define WS_POS_CNT 1          // int (total pos pairs, written by prep's sort block)
#define WS_SUM_POS 2
#define WS_S_POS   3
#define WS_G_OFF   8          // 151 floats
#define WS_BSUM_OFF 256       // NTILES floats: per-block gram sums (no atomics)
#define WS_LIST_OFF 4096      // posS, MAXP floats
#define MAXP (1 << 18)
#define WS_PAIR_OFF (WS_LIST_OFF + MAXP)          // MAXP int2 pair row-indices
#define WS_FEAT_OFF (WS_PAIR_OFF + 2 * MAXP)      // 4096x512 fp32 normalized feats
#define WS_FEATB_OFF (WS_FEAT_OFF + N * D)        // 4096x512 bf16 normalized feats

typedef __bf16 bf16x8 __attribute__((ext_vector_type(8)));
typedef float floatx4 __attribute__((ext_vector_type(4)));

// global->LDS async DMA, 16B per lane; LDS dest = wave-uniform base + lane*16
__device__ __forceinline__ void load_lds16(const void* g, void* s) {
    __builtin_amdgcn_global_load_lds(
        (const __attribute__((address_space(1))) void*)g,
        (__attribute__((address_space(3))) void*)s, 16, 0, 0);
}

// ---------------- K1: fused normalize (blocks 0..N-1) + sort/pair-list (block N) ----------------
__global__ __launch_bounds__(256) void k_prep(const float* __restrict__ feat,
                                              const int* __restrict__ cls,
                                              float* __restrict__ nf,
                                              __bf16* __restrict__ nfb,
                                              int2* __restrict__ pairRows,
                                              int* __restrict__ posCntOut,
                                              float* __restrict__ sPosOut) {
    __shared__ int shmem[NUM_CLASSES * 3 + N / 4];  // sort block scratch
    __shared__ int wsumR[4], wsumP[4];
    __shared__ float wsumF[4];
    int t = threadIdx.x;

    if (blockIdx.x < N) {
        // ---- normalize ----
        int row = blockIdx.x;
        const float* fr = feat + (size_t)row * D;
        float a = fr[t];
        float b = fr[t + 256];
        float ss = a * a + b * b;
        for (int o = 32; o > 0; o >>= 1) ss += __shfl_down(ss, o, 64);
        int lane = t & 63, wid = t >> 6;
        if (lane == 0) wsumF[wid] = ss;
        __syncthreads();
        float tot = wsumF[0] + wsumF[1] + wsumF[2] + wsumF[3];
        float inv = 1.0f / sqrtf(tot);
        float na = a * inv, nb = b * inv;
        nf[(size_t)row * D + t] = na;
        nf[(size_t)row * D + t + 256] = nb;
        nfb[(size_t)row * D + t] = (__bf16)na;
        nfb[(size_t)row * D + t + 256] = (__bf16)nb;
        return;
    }

    // ---- sort block: counting sort + prefix sums + flat pair list ----
    int* hcnt = shmem;
    int* hoff = shmem + NUM_CLASSES;
    int* poff = shmem + 2 * NUM_CLASSES;
    __shared__ int rowIdxL[N / 2];   // 4096 row ids packed 16-bit in 2048 ints
    for (int c = t; c < NUM_CLASSES; c += 256) hcnt[c] = 0;
    __syncthreads();
    for (int n = t; n < N; n += 256) atomicAdd(&hcnt[cls[n]], 1);
    __syncthreads();

    int c0 = t * 3;
    int cntPreR[3], cntPreP[3];
    int myR = 0, myP = 0;
    #pragma unroll
    for (int k = 0; k < 3; ++k) {
        int c = c0 + k;
        int cnt = (c < NUM_CLASSES) ? hcnt[c] : 0;
        cntPreR[k] = myR; cntPreP[k] = myP;
        myR += cnt;
        myP += cnt * (cnt - 1) / 2;
    }
    int lane = t & 63, wv = t >> 6;
    int incR = myR, incP = myP;
    for (int o = 1; o < 64; o <<= 1) {
        int rr = __shfl_up(incR, o, 64);
        int pp = __shfl_up(incP, o, 64);
        if (lane >= o) { incR += rr; incP += pp; }
    }
    if (lane == 63) { wsumR[wv] = incR; wsumP[wv] = incP; }
    __syncthreads();
    int baseR = 0, baseP = 0;
    for (int w = 0; w < wv; ++w) { baseR += wsumR[w]; baseP += wsumP[w]; }
    int exR = baseR + incR - myR;
    int exP = baseP + incP - myP;
    #pragma unroll
    for (int k = 0; k < 3; ++k) {
        int c = c0 + k;
        if (c < NUM_CLASSES) { hoff[c] = exR + cntPreR[k]; poff[c] = exP + cntPreP[k]; }
    }
    __syncthreads();

    for (int c = t; c < NUM_CLASSES; c += 256) hcnt[c] = hoff[c];   // cursors
    __syncthreads();
    for (int n = t; n < N; n += 256) {
        int p = atomicAdd(&hcnt[cls[n]], 1);
        int word = p >> 1, sh = (p & 1) * 16;
        atomicAnd(&rowIdxL[word], ~(0xFFFF << sh));
        atomicOr(&rowIdxL[word], (n & 0xFFFF) << sh);
    }
    __syncthreads();

    // build flat pair list
    for (int c = t; c < NUM_CLASSES; c += 256) {
        int o0 = hoff[c];
        int nc = (c + 1 < NUM_CLASSES ? hoff[c + 1]
                                      : wsumR[0] + wsumR[1] + wsumR[2] + wsumR[3]) - o0;
        int pb = poff[c];
        int idx = 0;
        for (int a = 0; a < nc - 1; ++a) {
            int sa = o0 + a;
            int ra = (rowIdxL[sa >> 1] >> ((sa & 1) * 16)) & 0xFFFF;
            for (int b = a + 1; b < nc; ++b) {
                int sb = o0 + b;
                int rb = (rowIdxL[sb >> 1] >> ((sb & 1) * 16)) & 0xFFFF;
                pairRows[pb + idx] = make_int2(ra, rb);
                ++idx;
            }
        }
    }
    if (t == 0) {
        int totP = wsumP[0] + wsumP[1] + wsumP[2] + wsumP[3];
        *posCntOut = totP;
        *sPosOut = (float)totP;
    }
}

// ---------------- K2: pair sims over flat list ----------------
__global__ __launch_bounds__(256) void k_pospairs4(const float* __restrict__ nf,
                                                   const int2* __restrict__ pairRows,
                                                   const int* __restrict__ posCnt,
                                                   float* __restrict__ posS) {
    int nP = *posCnt;
    if (nP > MAXP) nP = MAXP;
    int gw = (blockIdx.x * 256 + threadIdx.x) >> 6;   // global wave id, 0..4095
    int lane = threadIdx.x & 63;
    for (int p = gw; p < nP; p += 4096) {
        int2 pr = pairRows[p];
        const float4* x4 = (const float4*)(nf + (size_t)pr.x * D);
        const float4* y4 = (const float4*)(nf + (size_t)pr.y * D);
        float4 xa = x4[lane * 2], xb = x4[lane * 2 + 1];
        float4 ya = y4[lane * 2], yb = y4[lane * 2 + 1];
        float s = xa.x * ya.x + xa.y * ya.y + xa.z * ya.z + xa.w * ya.w
                + xb.x * yb.x + xb.y * yb.y + xb.z * yb.z + xb.w * yb.w;
        for (int o = 32; o > 0; o >>= 1) s += __shfl_down(s, o, 64);
        if (lane == 0) posS[p] = s;
    }
}

// ---------------- K3: hist_pos -> cdf -> G table, plus sum_pos g ----------------
__global__ __launch_bounds__(256) void k_build_cdf(const float* __restrict__ posS,
                                                   const int* __restrict__ posCnt,
                                                   float* __restrict__ G,
                                                   float* __restrict__ sumPosOut) {
    __shared__ float hist[NUM_STEPS];
    __shared__ float Gs[NUM_STEPS];
    int t = threadIdx.x;
    int C = *posCnt;
    if (C > MAXP) C = MAXP;
    for (int b = t; b < NUM_STEPS; b += 256) hist[b] = 0.f;
    __syncthreads();
    for (int p = t; p < C; p += 256) {
        float s = posS[p];
        float x = s * INV_STEP;
        float kf = floorf(x);
        float frac = x - kf;
        int kI = (int)kf;
        int lo = min(max(kI + HALF_BINS, 0), NUM_STEPS - 1);
        int hi = min(max(kI + HALF_BINS + 1, 0), NUM_STEPS - 1);
        atomicAdd(&hist[lo], 1.0f - frac);
        atomicAdd(&hist[hi], frac);
    }
    __syncthreads();
    if (t == 0) {
        float invC = (C > 0) ? (1.0f / (float)C) : 0.f;
        float acc = 0.f;
        for (int b = 0; b < NUM_STEPS; ++b) {
            acc += hist[b];
            Gs[b] = acc * invC;
        }
    }
    __syncthreads();
    for (int b = t; b < NUM_STEPS; b += 256) G[b] = Gs[b];
    float ps = 0.f;
    for (int p = t; p < C; p += 256) {
        float s = posS[p];
        float x = s * INV_STEP;
        float kf = floorf(x);
        float frac = x - kf;
        int kI = (int)kf;
        int lo = min(max(kI + HALF_BINS, 0), NUM_STEPS - 1);
        int hi = min(max(kI + HALF_BINS + 1, 0), NUM_STEPS - 1);
        ps += (1.f - frac) * Gs[lo] + frac * Gs[hi];
    }
    for (int o = 32; o > 0; o >>= 1) ps += __shfl_down(ps, o, 64);
    __shared__ float wsum[4];
    int lane = t & 63, wid = t >> 6;
    if (lane == 0) wsum[wid] = ps;
    __syncthreads();
    if (t == 0) *sumPosOut = wsum[0] + wsum[1] + wsum[2] + wsum[3];
}

// ---------------- K4: 64x64 MFMA Gram tiles, 2080 blocks, no atomics ----------------
// LDS: 4 panels/matrix; panel p holds tile rows p*16..p*16+15, 32 k, in MFMA fragment
// lane order: element (row = L&15, k = (L>>4)*8 + j) at p*512 + L*8 + j.
// Staging: wave w DMAs panel w of A and of B (global_load_lds, lane*16B dest).
// Compute: 2x2 wave grid; wave tile 32x32 via 2x2 of 16x16x32 MFMA (acc[2][2]).
__global__ __launch_bounds__(256) void k_gram(const __bf16* __restrict__ nfb,
                                              const float* __restrict__ G,
                                              float* __restrict__ blockSums) {
    int bid = blockIdx.x;
    int ti = 0, rem = bid;
    while (rem >= GTILES - ti) { rem -= GTILES - ti; ++ti; }
    int tj = ti + rem;

    __shared__ __align__(16) __bf16 As[4 * 512];   // 4 KiB
    __shared__ __align__(16) __bf16 Bs[4 * 512];
    __shared__ float Gs[NUM_STEPS];

    int tid = threadIdx.x;
    for (int b = tid; b < NUM_STEPS; b += 256) Gs[b] = G[b];

    int lane = tid & 63;
    int wave = tid >> 6;
    int rh = wave >> 1, ch = wave & 1;
    int rowA0 = ti * 64, rowB0 = tj * 64;

    // staging addresses: wave stages panel `wave` of A and of B
    int fr2 = lane & 15, kc2 = lane >> 4;
    const __bf16* gA = nfb + (size_t)(rowA0 + wave * 16 + fr2) * D + kc2 * 8;
    const __bf16* gB = nfb + (size_t)(rowB0 + wave * 16 + fr2) * D + kc2 * 8;
    __bf16* lA = &As[wave * 512];
    __bf16* lB = &Bs[wave * 512];

    floatx4 acc[2][2] = {};

    for (int kb = 0; kb < D / 32; ++kb) {
        int kbase = kb * 32;
        load_lds16(gA + kbase, lA);
        load_lds16(gB + kbase, lB);
        __syncthreads();

        bf16x8 a[2], b[2];
        #pragma unroll
        for (int r = 0; r < 2; ++r)
            a[r] = *(const bf16x8*)(&As[(rh * 2 + r) * 512 + lane * 8]);
        #pragma unroll
        for (int c = 0; c < 2; ++c)
            b[c] = *(const bf16x8*)(&Bs[(ch * 2 + c) * 512 + lane * 8]);
        #pragma unroll
        for (int r = 0; r < 2; ++r)
            #pragma unroll
            for (int c = 0; c < 2; ++c)
                acc[r][c] = __builtin_amdgcn_mfma_f32_16x16x32_bf16(a[r], b[c], acc[r][c], 0, 0, 0);
        __syncthreads();
    }

    // epilogue: g(s) lookup with upper-triangle mask
    // C/D layout (16x16x32): col = lane&15 (B index), row = (lane>>4)*4 + reg (A index)
    int crow = (lane >> 4) * 4;
    int ccol = lane & 15;
    float gsum = 0.f;
    #pragma unroll
    for (int r = 0; r < 2; ++r) {
        #pragma unroll
        for (int c = 0; c < 2; ++c) {
            #pragma unroll
            for (int reg = 0; reg < 4; ++reg) {
                int gi = rowA0 + rh * 32 + r * 16 + crow + reg;
                int gj = rowB0 + ch * 32 + c * 16 + ccol;
                if (gi < gj) {
                    float s = acc[r][c][reg];
                    float x = s * INV_STEP;
                    float kf = floorf(x);
                    float frac = x - kf;
                    int kI = (int)kf;
                    int lo = min(max(kI + HALF_BINS, 0), NUM_STEPS - 1);
                    int hi = min(max(kI + HALF_BINS + 1, 0), NUM_STEPS - 1);
                    gsum += (1.f - frac) * Gs[lo] + frac * Gs[hi];
                }
            }
        }
    }
    for (int o = 32; o > 0; o >>= 1) gsum += __shfl_down(gsum, o, 64);
    __shared__ float wsum[4];
    if ((tid & 63) == 0) wsum[tid >> 6] = gsum;
    __syncthreads();
    if (tid == 0) blockSums[bid] = wsum[0] + wsum[1] + wsum[2] + wsum[3];
}

// ---------------- K5: deterministic final reduce + combine ----------------
__global__ __launch_bounds__(256) void k_final(const float* __restrict__ blockSums,
                                               const float* __restrict__ wsf,
                                               float* __restrict__ out) {
    int t = threadIdx.x;
    float s = 0.f;
    for (int i = t; i < NTILES; i += 256) s += blockSums[i];
    for (int o = 32; o > 0; o >>= 1) s += __shfl_down(s, o, 64);
    __shared__ float wsum[4];
    if ((t & 63) == 0) wsum[t >> 6] = s;
    __syncthreads();
    if (t == 0) {
        float sAll = wsum[0] + wsum[1] + wsum[2] + wsum[3];
        float sPos = wsf[WS_SUM_POS];
        float C = wsf[WS_S_POS];
        out[0] = (sAll - sPos) / (P_TOTAL - C);
    }
}

extern "C" void kernel_launch(void* const* d_in, const int* in_sizes, int n_in,
                              void* d_out, int out_size, void* d_ws, size_t ws_size,
                              hipStream_t stream) {
    const float* feat = (const float*)d_in[0];
    const int* cls = (const int*)d_in[1];
    float* out = (float*)d_out;
    float* wsf = (float*)d_ws;
    int* wsi = (int*)d_ws;

    hipMemsetAsync(d_ws, 0, 1024, stream);   // zero counters / G header

    float* nf = wsf + WS_FEAT_OFF;
    __bf16* nfb = (__bf16*)(wsf + WS_FEATB_OFF);
    float* posS = wsf + WS_LIST_OFF;
    int2* pairRows = (int2*)(wsi + WS_PAIR_OFF);
    float* G = wsf + WS_G_OFF;
    float* blockSums = wsf + WS_BSUM_OFF;

    k_prep<<<N + 1, 256, 0, stream>>>(feat, cls, nf, nfb, pairRows,
                                      wsi + WS_POS_CNT, wsf + WS_S_POS);
    k_pospairs4<<<1024, 256, 0, stream>>>(nf, pairRows, wsi + WS_POS_CNT, posS);
    k_build_cdf<<<1, 256, 0, stream>>>(posS, wsi + WS_POS_CNT, G, wsf + WS_SUM_POS);
    k_gram<<<NTILES, 256, 0, stream>>>(nfb, G, blockSums);
    k_final<<<1, 256, 0, stream>>>(blockSums, wsf, out);
}

// Round 10
// 162.924 us; speedup vs baseline: 1.1342x; 1.0604x over previous
//
#include <hip/hip_runtime.h>
#include <math.h>

#define N 4096
#define D 512
#define NUM_STEPS 151
#define HALF_BINS 75
#define INV_STEP 75.0f
#define NUM_CLASSES 751
#define P_TOTAL 8386560.0f   // N*(N-1)/2, exact in fp32 (< 2^24)
#define TILES_1D 32          // 4096 / 128
#define NTILES (TILES_1D * (TILES_1D + 1) / 2)   // 528 upper-tri 128x128 tiles

// ws layout (float/int indices into d_ws)
#define WS_SUM_ALL 0
#define WS_POS_CNT 1          // int (total pos pairs, written by prep's sort block)
#define WS_SUM_POS 2
#define WS_S_POS   3
#define WS_G_OFF   8          // 151 floats
#define WS_BSUM_OFF 256       // NTILES floats: per-block gram sums (no atomics)
#define WS_LIST_OFF 4096      // posS, MAXP floats
#define MAXP (1 << 18)
#define WS_PAIR_OFF (WS_LIST_OFF + MAXP)          // MAXP int2 pair row-indices
#define WS_FEAT_OFF (WS_PAIR_OFF + 2 * MAXP)      // 4096x512 fp32 normalized feats
#define WS_FEATB_OFF (WS_FEAT_OFF + N * D)        // 4096x512 bf16 normalized feats

typedef __bf16 bf16x8 __attribute__((ext_vector_type(8)));
typedef float floatx4 __attribute__((ext_vector_type(4)));

// ---------------- K1: fused normalize (blocks 0..N-1) + sort/pair-list (block N) ----------------
__global__ __launch_bounds__(256) void k_prep(const float* __restrict__ feat,
                                              const int* __restrict__ cls,
                                              float* __restrict__ nf,
                                              __bf16* __restrict__ nfb,
                                              int2* __restrict__ pairRows,
                                              int* __restrict__ posCntOut,
                                              float* __restrict__ sPosOut) {
    __shared__ int shmem[NUM_CLASSES * 3 + N / 4];  // sort block scratch
    __shared__ int wsumR[4], wsumP[4];
    __shared__ float wsumF[4];
    int t = threadIdx.x;

    if (blockIdx.x < N) {
        // ---- normalize ----
        int row = blockIdx.x;
        const float* fr = feat + (size_t)row * D;
        float a = fr[t];
        float b = fr[t + 256];
        float ss = a * a + b * b;
        for (int o = 32; o > 0; o >>= 1) ss += __shfl_down(ss, o, 64);
        int lane = t & 63, wid = t >> 6;
        if (lane == 0) wsumF[wid] = ss;
        __syncthreads();
        float tot = wsumF[0] + wsumF[1] + wsumF[2] + wsumF[3];
        float inv = 1.0f / sqrtf(tot);
        float na = a * inv, nb = b * inv;
        nf[(size_t)row * D + t] = na;
        nf[(size_t)row * D + t + 256] = nb;
        nfb[(size_t)row * D + t] = (__bf16)na;
        nfb[(size_t)row * D + t + 256] = (__bf16)nb;
        return;
    }

    // ---- sort block: counting sort + prefix sums + flat pair list ----
    int* hcnt = shmem;
    int* hoff = shmem + NUM_CLASSES;
    int* poff = shmem + 2 * NUM_CLASSES;
    __shared__ int rowIdxL[N / 2];   // 4096 row ids packed 16-bit in 2048 ints
    for (int c = t; c < NUM_CLASSES; c += 256) hcnt[c] = 0;
    __syncthreads();
    for (int n = t; n < N; n += 256) atomicAdd(&hcnt[cls[n]], 1);
    __syncthreads();

    int c0 = t * 3;
    int cntPreR[3], cntPreP[3];
    int myR = 0, myP = 0;
    #pragma unroll
    for (int k = 0; k < 3; ++k) {
        int c = c0 + k;
        int cnt = (c < NUM_CLASSES) ? hcnt[c] : 0;
        cntPreR[k] = myR; cntPreP[k] = myP;
        myR += cnt;
        myP += cnt * (cnt - 1) / 2;
    }
    int lane = t & 63, wv = t >> 6;
    int incR = myR, incP = myP;
    for (int o = 1; o < 64; o <<= 1) {
        int rr = __shfl_up(incR, o, 64);
        int pp = __shfl_up(incP, o, 64);
        if (lane >= o) { incR += rr; incP += pp; }
    }
    if (lane == 63) { wsumR[wv] = incR; wsumP[wv] = incP; }
    __syncthreads();
    int baseR = 0, baseP = 0;
    for (int w = 0; w < wv; ++w) { baseR += wsumR[w]; baseP += wsumP[w]; }
    int exR = baseR + incR - myR;
    int exP = baseP + incP - myP;
    #pragma unroll
    for (int k = 0; k < 3; ++k) {
        int c = c0 + k;
        if (c < NUM_CLASSES) { hoff[c] = exR + cntPreR[k]; poff[c] = exP + cntPreP[k]; }
    }
    __syncthreads();

    for (int c = t; c < NUM_CLASSES; c += 256) hcnt[c] = hoff[c];   // cursors
    __syncthreads();
    for (int n = t; n < N; n += 256) {
        int p = atomicAdd(&hcnt[cls[n]], 1);
        int word = p >> 1, sh = (p & 1) * 16;
        atomicAnd(&rowIdxL[word], ~(0xFFFF << sh));
        atomicOr(&rowIdxL[word], (n & 0xFFFF) << sh);
    }
    __syncthreads();

    // build flat pair list
    for (int c = t; c < NUM_CLASSES; c += 256) {
        int o0 = hoff[c];
        int nc = (c + 1 < NUM_CLASSES ? hoff[c + 1]
                                      : wsumR[0] + wsumR[1] + wsumR[2] + wsumR[3]) - o0;
        int pb = poff[c];
        int idx = 0;
        for (int a = 0; a < nc - 1; ++a) {
            int sa = o0 + a;
            int ra = (rowIdxL[sa >> 1] >> ((sa & 1) * 16)) & 0xFFFF;
            for (int b = a + 1; b < nc; ++b) {
                int sb = o0 + b;
                int rb = (rowIdxL[sb >> 1] >> ((sb & 1) * 16)) & 0xFFFF;
                pairRows[pb + idx] = make_int2(ra, rb);
                ++idx;
            }
        }
    }
    if (t == 0) {
        int totP = wsumP[0] + wsumP[1] + wsumP[2] + wsumP[3];
        *posCntOut = totP;
        *sPosOut = (float)totP;
    }
}

// ---------------- K2: pair sims over flat list ----------------
__global__ __launch_bounds__(256) void k_pospairs4(const float* __restrict__ nf,
                                                   const int2* __restrict__ pairRows,
                                                   const int* __restrict__ posCnt,
                                                   float* __restrict__ posS) {
    int nP = *posCnt;
    if (nP > MAXP) nP = MAXP;
    int gw = (blockIdx.x * 256 + threadIdx.x) >> 6;   // global wave id, 0..4095
    int lane = threadIdx.x & 63;
    for (int p = gw; p < nP; p += 4096) {
        int2 pr = pairRows[p];
        const float4* x4 = (const float4*)(nf + (size_t)pr.x * D);
        const float4* y4 = (const float4*)(nf + (size_t)pr.y * D);
        float4 xa = x4[lane * 2], xb = x4[lane * 2 + 1];
        float4 ya = y4[lane * 2], yb = y4[lane * 2 + 1];
        float s = xa.x * ya.x + xa.y * ya.y + xa.z * ya.z + xa.w * ya.w
                + xb.x * yb.x + xb.y * yb.y + xb.z * yb.z + xb.w * yb.w;
        for (int o = 32; o > 0; o >>= 1) s += __shfl_down(s, o, 64);
        if (lane == 0) posS[p] = s;
    }
}

// ---------------- K3: hist_pos -> cdf -> G table, plus sum_pos g ----------------
__global__ __launch_bounds__(256) void k_build_cdf(const float* __restrict__ posS,
                                                   const int* __restrict__ posCnt,
                                                   float* __restrict__ G,
                                                   float* __restrict__ sumPosOut) {
    __shared__ float hist[NUM_STEPS];
    __shared__ float Gs[NUM_STEPS];
    int t = threadIdx.x;
    int C = *posCnt;
    if (C > MAXP) C = MAXP;
    for (int b = t; b < NUM_STEPS; b += 256) hist[b] = 0.f;
    __syncthreads();
    for (int p = t; p < C; p += 256) {
        float s = posS[p];
        float x = s * INV_STEP;
        float kf = floorf(x);
        float frac = x - kf;
        int kI = (int)kf;
        int lo = min(max(kI + HALF_BINS, 0), NUM_STEPS - 1);
        int hi = min(max(kI + HALF_BINS + 1, 0), NUM_STEPS - 1);
        atomicAdd(&hist[lo], 1.0f - frac);
        atomicAdd(&hist[hi], frac);
    }
    __syncthreads();
    if (t == 0) {
        float invC = (C > 0) ? (1.0f / (float)C) : 0.f;
        float acc = 0.f;
        for (int b = 0; b < NUM_STEPS; ++b) {
            acc += hist[b];
            Gs[b] = acc * invC;
        }
    }
    __syncthreads();
    for (int b = t; b < NUM_STEPS; b += 256) G[b] = Gs[b];
    float ps = 0.f;
    for (int p = t; p < C; p += 256) {
        float s = posS[p];
        float x = s * INV_STEP;
        float kf = floorf(x);
        float frac = x - kf;
        int kI = (int)kf;
        int lo = min(max(kI + HALF_BINS, 0), NUM_STEPS - 1);
        int hi = min(max(kI + HALF_BINS + 1, 0), NUM_STEPS - 1);
        ps += (1.f - frac) * Gs[lo] + frac * Gs[hi];
    }
    for (int o = 32; o > 0; o >>= 1) ps += __shfl_down(ps, o, 64);
    __shared__ float wsum[4];
    int lane = t & 63, wid = t >> 6;
    if (lane == 0) wsum[wid] = ps;
    __syncthreads();
    if (t == 0) *sumPosOut = wsum[0] + wsum[1] + wsum[2] + wsum[3];
}

// ---------------- K4: 128x128 MFMA Gram, 512 threads, dbuf LDS, 1 barrier/iter ----------------
// LDS: per buffer, 8 panels/matrix; panel p = rows p*16..p*16+15 x 32 k, in MFMA
// fragment lane order: element (row = L&15, k = (L>>4)*8 + j) at p*512 + L*8 + j.
// Staging: wave w loads panel w of A and of B into VGPRs (global float4, lane*16B),
// writes into the NEXT LDS buffer while MFMAs consume the current one.
// Compute: 8 waves in 4x2 grid; wave = 32 rows x 64 cols = 2x4 of 16x16x32 MFMA.
__global__ __launch_bounds__(512) void k_gram(const __bf16* __restrict__ nfb,
                                              const float* __restrict__ G,
                                              float* __restrict__ blockSums) {
    int bid = blockIdx.x;
    int ti = 0, rem = bid;
    while (rem >= TILES_1D - ti) { rem -= TILES_1D - ti; ++ti; }
    int tj = ti + rem;

    __shared__ __align__(16) __bf16 As[2][8 * 512];   // 2 x 8 KiB
    __shared__ __align__(16) __bf16 Bs[2][8 * 512];
    __shared__ float Gs[NUM_STEPS];

    int tid = threadIdx.x;
    for (int b = tid; b < NUM_STEPS; b += 512) Gs[b] = G[b];

    int lane = tid & 63;
    int wave = tid >> 6;          // 0..7
    int wr = wave >> 1;           // 0..3  (A row-half: 2 panels)
    int wc = wave & 1;            // 0..1  (B col-half: 4 panels)
    int rowA0 = ti * 128, rowB0 = tj * 128;

    // staging: wave stages panel `wave` of A and of B
    int fr2 = lane & 15, kc2 = lane >> 4;
    const __bf16* gA = nfb + (size_t)(rowA0 + wave * 16 + fr2) * D + kc2 * 8;
    const __bf16* gB = nfb + (size_t)(rowB0 + wave * 16 + fr2) * D + kc2 * 8;
    int ldsSlot = wave * 512 + lane * 8;

    floatx4 acc[2][4] = {};

    // preload kb=0 and fill buffer 0
    float4 ra = *(const float4*)(gA);
    float4 rb = *(const float4*)(gB);
    *(float4*)(&As[0][ldsSlot]) = ra;
    *(float4*)(&Bs[0][ldsSlot]) = rb;

    for (int kb = 0; kb < D / 32; ++kb) {
        __syncthreads();                       // publishes buffer kb&1
        int cur = kb & 1;
        if (kb < D / 32 - 1) {                 // issue next-iter global loads early
            ra = *(const float4*)(gA + (kb + 1) * 32);
            rb = *(const float4*)(gB + (kb + 1) * 32);
        }

        bf16x8 a[2], b[4];
        #pragma unroll
        for (int r = 0; r < 2; ++r)
            a[r] = *(const bf16x8*)(&As[cur][(wr * 2 + r) * 512 + lane * 8]);
        #pragma unroll
        for (int c = 0; c < 4; ++c)
            b[c] = *(const bf16x8*)(&Bs[cur][(wc * 4 + c) * 512 + lane * 8]);
        #pragma unroll
        for (int r = 0; r < 2; ++r)
            #pragma unroll
            for (int c = 0; c < 4; ++c)
                acc[r][c] = __builtin_amdgcn_mfma_f32_16x16x32_bf16(a[r], b[c], acc[r][c], 0, 0, 0);

        if (kb < D / 32 - 1) {                 // write next buffer (read after next barrier)
            *(float4*)(&As[cur ^ 1][ldsSlot]) = ra;
            *(float4*)(&Bs[cur ^ 1][ldsSlot]) = rb;
        }
    }

    // epilogue: g(s) lookup with upper-triangle mask
    // C/D layout (16x16x32): col = lane&15 (B index), row = (lane>>4)*4 + reg (A index)
    int crow = (lane >> 4) * 4;
    int ccol = lane & 15;
    float gsum = 0.f;
    #pragma unroll
    for (int r = 0; r < 2; ++r) {
        #pragma unroll
        for (int c = 0; c < 4; ++c) {
            #pragma unroll
            for (int reg = 0; reg < 4; ++reg) {
                int gi = rowA0 + (wr * 2 + r) * 16 + crow + reg;
                int gj = rowB0 + (wc * 4 + c) * 16 + ccol;
                if (gi < gj) {
                    float s = acc[r][c][reg];
                    float x = s * INV_STEP;
                    float kf = floorf(x);
                    float frac = x - kf;
                    int kI = (int)kf;
                    int lo = min(max(kI + HALF_BINS, 0), NUM_STEPS - 1);
                    int hi = min(max(kI + HALF_BINS + 1, 0), NUM_STEPS - 1);
                    gsum += (1.f - frac) * Gs[lo] + frac * Gs[hi];
                }
            }
        }
    }
    for (int o = 32; o > 0; o >>= 1) gsum += __shfl_down(gsum, o, 64);
    __shared__ float wsum[8];
    if ((tid & 63) == 0) wsum[tid >> 6] = gsum;
    __syncthreads();
    if (tid == 0) {
        float s = 0.f;
        #pragma unroll
        for (int w = 0; w < 8; ++w) s += wsum[w];
        blockSums[bid] = s;
    }
}

// ---------------- K5: deterministic final reduce + combine ----------------
__global__ __launch_bounds__(256) void k_final(const float* __restrict__ blockSums,
                                               const float* __restrict__ wsf,
                                               float* __restrict__ out) {
    int t = threadIdx.x;
    float s = 0.f;
    for (int i = t; i < NTILES; i += 256) s += blockSums[i];
    for (int o = 32; o > 0; o >>= 1) s += __shfl_down(s, o, 64);
    __shared__ float wsum[4];
    if ((t & 63) == 0) wsum[t >> 6] = s;
    __syncthreads();
    if (t == 0) {
        float sAll = wsum[0] + wsum[1] + wsum[2] + wsum[3];
        float sPos = wsf[WS_SUM_POS];
        float C = wsf[WS_S_POS];
        out[0] = (sAll - sPos) / (P_TOTAL - C);
    }
}

extern "C" void kernel_launch(void* const* d_in, const int* in_sizes, int n_in,
                              void* d_out, int out_size, void* d_ws, size_t ws_size,
                              hipStream_t stream) {
    const float* feat = (const float*)d_in[0];
    const int* cls = (const int*)d_in[1];
    float* out = (float*)d_out;
    float* wsf = (float*)d_ws;
    int* wsi = (int*)d_ws;

    hipMemsetAsync(d_ws, 0, 1024, stream);   // zero counters / G header

    float* nf = wsf + WS_FEAT_OFF;
    __bf16* nfb = (__bf16*)(wsf + WS_FEATB_OFF);
    float* posS = wsf + WS_LIST_OFF;
    int2* pairRows = (int2*)(wsi + WS_PAIR_OFF);
    float* G = wsf + WS_G_OFF;
    float* blockSums = wsf + WS_BSUM_OFF;

    k_prep<<<N + 1, 256, 0, stream>>>(feat, cls, nf, nfb, pairRows,
                                      wsi + WS_POS_CNT, wsf + WS_S_POS);
    k_pospairs4<<<1024, 256, 0, stream>>>(nf, pairRows, wsi + WS_POS_CNT, posS);
    k_build_cdf<<<1, 256, 0, stream>>>(posS, wsi + WS_POS_CNT, G, wsf + WS_SUM_POS);
    k_gram<<<NTILES, 512, 0, stream>>>(nfb, G, blockSums);
    k_final<<<1, 256, 0, stream>>>(blockSums, wsf, out);
}